// Round 1
// baseline (490.880 us; speedup 1.0000x reference)
//
#include <hip/hip_runtime.h>
#include <hip/hip_bf16.h>
#include <stdint.h>
#include <stddef.h>

// Problem constants (from reference setup_inputs)
#define N_NODES 8192
#define DIM     256
#define BATCH   4096
#define CLASSES 1000
#define ALPHA_C 1.0f
#define BETA_C  0.01f
#define GAMMA_C 0.1f

typedef __bf16 bf16_t;
typedef __bf16 bf16x8 __attribute__((ext_vector_type(8)));
typedef __bf16 bf16x4 __attribute__((ext_vector_type(4)));
typedef float  f32x4  __attribute__((ext_vector_type(4)));
typedef float  f32x16 __attribute__((ext_vector_type(16)));

// Async global->LDS DMA, 16 B/lane, dest = wave-uniform base + lane*16.
__device__ __forceinline__ void async16(const void* g, void* l) {
  __builtin_amdgcn_global_load_lds(
      (const __attribute__((address_space(1))) uint32_t*)g,
      (__attribute__((address_space(3))) uint32_t*)l, 16, 0, 0);
}

// ---------------------------------------------------------------------------
// Prep: L2-normalize each embedding row (fp32 math) and store bf16 U[N][D].
// ---------------------------------------------------------------------------
__global__ __launch_bounds__(256) void prep_kernel(
    const float* __restrict__ emb, bf16_t* __restrict__ U) {
  const int row = blockIdx.x;
  const int t = threadIdx.x;
  const float v = emb[(size_t)row * DIM + t];
  float sq = v * v;
  for (int off = 32; off; off >>= 1) sq += __shfl_down(sq, off);
  __shared__ float red[4];
  if ((t & 63) == 0) red[t >> 6] = sq;
  __syncthreads();
  const float total = red[0] + red[1] + red[2] + red[3];
  U[(size_t)row * DIM + t] = (bf16_t)(v * rsqrtf(total));
}

// ---------------------------------------------------------------------------
// Transpose U[N][D] -> Ut[D][N] (bf16), 64x64 tiles through LDS.
// Needed so the GEMM A-operand (Ut rows = U columns) is K-contiguous.
// ---------------------------------------------------------------------------
__global__ __launch_bounds__(256) void transpose_kernel(
    const bf16_t* __restrict__ U, bf16_t* __restrict__ Ut) {
  __shared__ bf16_t tile[64][72];  // +8 pad: dodge bank conflicts
  const int i0 = blockIdx.x * 64, d0 = blockIdx.y * 64;
  const int t = threadIdx.x;
  const int r = t >> 3, c8 = (t & 7) * 8;
#pragma unroll
  for (int it = 0; it < 2; ++it) {
    const int row = r + it * 32;
    *(bf16x8*)&tile[row][c8] =
        *(const bf16x8*)&U[(size_t)(i0 + row) * DIM + d0 + c8];
  }
  __syncthreads();
#pragma unroll
  for (int it = 0; it < 2; ++it) {
    const int d = r + it * 32;
    bf16x8 v;
#pragma unroll
    for (int j = 0; j < 8; ++j) v[j] = tile[c8 + j][d];
    *(bf16x8*)&Ut[(size_t)(d0 + d) * N_NODES + i0 + c8] = v;
  }
}

// ---------------------------------------------------------------------------
// Cross-entropy: one block per batch row; single global pass, logits in regs.
// ---------------------------------------------------------------------------
__global__ __launch_bounds__(256) void ce_kernel(
    const float* __restrict__ pred, const int* __restrict__ target,
    float* __restrict__ out) {
  const int row = blockIdx.x;
  const int t = threadIdx.x;
  const float* p = pred + (size_t)row * CLASSES;

  float v[4];
  for (int k = 0; k < 4; ++k) {
    const int c = t + k * 256;
    v[k] = (c < CLASSES) ? p[c] : -INFINITY;
  }

  float m = fmaxf(fmaxf(v[0], v[1]), fmaxf(v[2], v[3]));
  for (int off = 32; off; off >>= 1) m = fmaxf(m, __shfl_down(m, off));

  __shared__ float red[8];
  const int wave = t >> 6, lane = t & 63;
  if (lane == 0) red[wave] = m;
  __syncthreads();
  if (t == 0) red[4] = fmaxf(fmaxf(red[0], red[1]), fmaxf(red[2], red[3]));
  __syncthreads();
  const float mx = red[4];

  float s = 0.f;
  for (int k = 0; k < 4; ++k) s += __expf(v[k] - mx);
  for (int off = 32; off; off >>= 1) s += __shfl_down(s, off);
  if (lane == 0) red[wave] = s;
  __syncthreads();
  if (t == 0) {
    float ssum = red[0] + red[1] + red[2] + red[3];
    float lse = mx + __logf(ssum);
    float loss = lse - p[target[row]];
    atomicAdd(out, loss * (ALPHA_C / (float)BATCH));
  }
}

// ---------------------------------------------------------------------------
// Semantic kernel via trace identity:
//   sum_ij a_ij*sim_ij = tr(U^T A U),  tr = sum_i U_i . W_i,  W = A*U
// Block = 64 adj rows (i-strip) x 1024 adj cols (K-chunk). MFMA orientation:
//   a-frag = Ut[d][k-contig] (bf16), b-frag = adj[i][k-contig] (f32->bf16),
//   D[row-pattern=d][col=i] accumulates W[i][d] partials in registers.
// Fused in the staging/fragment path (exactly-once coverage on wm==0 waves):
//   s_abs = sum|a| (BETA term), s_sum = sum a (GAMMA * 1 term).
// Epilogue: trace contribution from acc x U[i][d] gathers; W never hits HBM.
// adj read exactly once, as the pipelined GEMM operand (gload_lds w=16 into
// XOR-swizzled LDS; chunk p of row R holds global chunk p^(R&mask)).
// ---------------------------------------------------------------------------
#define BN 64
#define BK 64
#define KC 8
#define KW (N_NODES / KC)   // 1024
#define NCHUNK (KW / BK)    // 16

__global__ __launch_bounds__(256, 3) void semantic_kernel(
    const float* __restrict__ adj, const bf16_t* __restrict__ U,
    const bf16_t* __restrict__ Ut, float* __restrict__ out) {
  __shared__ __align__(16) bf16_t lds_ut[DIM * BK];  // 32 KB [d][64k] swizzled
  __shared__ __align__(16) float  lds_a[BN * BK];    // 16 KB [i][64k] swizzled
  __shared__ float red[4];

  const int t = threadIdx.x;
  const int w = t >> 6, lane = t & 63;
  const int wm = w >> 1, wn = w & 1;  // wave-M (d half), wave-N (i half)
  const int m = lane & 31, h = lane >> 5;
  const int i0 = blockIdx.x * BN;
  const int k0 = blockIdx.y * KW;

  f32x16 acc[4] = {};  // mr=0..3: d = wm*128 + mr*32 + C-row-pattern
  float s_abs = 0.f, s_sum = 0.f;

  // Staging lane maps. Ut: 8 lanes/row (8x16B chunks), swizzle c^(r&7).
  const int ut_rl = lane >> 3;          // row within 8-row group
  const int ut_c = (lane & 7) ^ ut_rl;  // source chunk for LDS pos lane&7
  // adj: 16 lanes/row (16x16B chunks), swizzle c^(r&15).
  const int a_rl = lane >> 4;

  for (int ck = 0; ck < NCHUNK; ++ck) {
    const int ko = k0 + ck * BK;
    // Stage Ut slab [256][64] bf16: each wave 8 rows/iter x 8 iters.
#pragma unroll
    for (int ii = 0; ii < 8; ++ii) {
      const int rbase = ii * 32 + w * 8;  // wave-uniform
      async16(Ut + (size_t)(rbase + ut_rl) * N_NODES + ko + ut_c * 8,
              &lds_ut[rbase * BK]);
    }
    // Stage adj tile [64][64] f32: each wave 4 rows/iter x 4 iters.
#pragma unroll
    for (int ii = 0; ii < 4; ++ii) {
      const int rbase = w * 16 + ii * 4;  // wave-uniform
      const int r = rbase + a_rl;
      const int c = (lane & 15) ^ (r & 15);
      async16(adj + (size_t)(i0 + r) * N_NODES + ko + c * 4,
              &lds_a[rbase * BK]);
    }
    __syncthreads();
#pragma unroll
    for (int kk = 0; kk < 4; ++kk) {
      bf16x8 af[4];
#pragma unroll
      for (int mr = 0; mr < 4; ++mr) {
        const int rd = wm * 128 + mr * 32 + m;
        af[mr] = *(const bf16x8*)
            &lds_ut[rd * BK + (((kk * 2 + h) ^ (rd & 7)) * 8)];
      }
      const int ri = wn * 32 + m;
      const int c0 = kk * 4 + h * 2;  // global 16B chunk: k = kk*16 + h*8
      const f32x4 b0 =
          *(const f32x4*)&lds_a[ri * BK + ((c0 ^ (ri & 15)) * 4)];
      const f32x4 b1 =
          *(const f32x4*)&lds_a[ri * BK + (((c0 + 1) ^ (ri & 15)) * 4)];
      if (wm == 0) {  // each adj element counted exactly once
        s_abs += fabsf(b0[0]) + fabsf(b0[1]) + fabsf(b0[2]) + fabsf(b0[3]) +
                 fabsf(b1[0]) + fabsf(b1[1]) + fabsf(b1[2]) + fabsf(b1[3]);
        s_sum += b0[0] + b0[1] + b0[2] + b0[3] + b1[0] + b1[1] + b1[2] + b1[3];
      }
      bf16x8 bb;
      bb[0] = (bf16_t)b0[0]; bb[1] = (bf16_t)b0[1];
      bb[2] = (bf16_t)b0[2]; bb[3] = (bf16_t)b0[3];
      bb[4] = (bf16_t)b1[0]; bb[5] = (bf16_t)b1[1];
      bb[6] = (bf16_t)b1[2]; bb[7] = (bf16_t)b1[3];
#pragma unroll
      for (int mr = 0; mr < 4; ++mr)
        acc[mr] = __builtin_amdgcn_mfma_f32_32x32x16_bf16(af[mr], bb, acc[mr],
                                                          0, 0, 0);
    }
    __syncthreads();
  }

  // Trace epilogue: C/D layout col = lane&31 = i-rel, row = (r&3)+8*(r>>2)+4h.
  float tr = 0.f;
  const bf16_t* Urow = U + (size_t)(i0 + wn * 32 + m) * DIM;
#pragma unroll
  for (int mr = 0; mr < 4; ++mr) {
#pragma unroll
    for (int rq = 0; rq < 4; ++rq) {
      const int d = wm * 128 + mr * 32 + rq * 8 + h * 4;
      const bf16x4 uu = *(const bf16x4*)&Urow[d];
      tr += acc[mr][rq * 4 + 0] * (float)uu[0] +
            acc[mr][rq * 4 + 1] * (float)uu[1] +
            acc[mr][rq * 4 + 2] * (float)uu[2] +
            acc[mr][rq * 4 + 3] * (float)uu[3];
    }
  }

  float contrib = -GAMMA_C * tr;
  if (wm == 0) contrib += BETA_C * s_abs + GAMMA_C * s_sum;
  for (int off = 32; off; off >>= 1) contrib += __shfl_down(contrib, off);
  if (lane == 0) red[w] = contrib;
  __syncthreads();
  if (t == 0) {
    const float inv = 1.f / ((float)N_NODES * (float)N_NODES);
    atomicAdd(out, (red[0] + red[1] + red[2] + red[3]) * inv);
  }
}

// ---------------------------------------------------------------------------
extern "C" void kernel_launch(void* const* d_in, const int* in_sizes, int n_in,
                              void* d_out, int out_size, void* d_ws,
                              size_t ws_size, hipStream_t stream) {
  const float* pred   = (const float*)d_in[0];
  const int*   target = (const int*)d_in[1];
  const float* adj    = (const float*)d_in[2];
  const float* emb    = (const float*)d_in[3];
  float* out = (float*)d_out;

  bf16_t* U  = (bf16_t*)d_ws;                   // 4 MB normalized rows [N][D]
  bf16_t* Ut = U + (size_t)N_NODES * DIM;       // 4 MB transposed [D][N]

  hipMemsetAsync(d_out, 0, sizeof(float), stream);
  prep_kernel<<<N_NODES, 256, 0, stream>>>(emb, U);
  transpose_kernel<<<dim3(N_NODES / 64, DIM / 64), 256, 0, stream>>>(U, Ut);
  ce_kernel<<<BATCH, 256, 0, stream>>>(pred, target, out);
  semantic_kernel<<<dim3(N_NODES / BN, KC), 256, 0, stream>>>(adj, U, Ut, out);
}